// Round 6
// baseline (193.769 us; speedup 1.0000x reference)
//
#include <hip/hip_runtime.h>
#include <hip/hip_bf16.h>
#include <stdint.h>

// Problem constants
#define B_DIM 8
#define S_DIM 4096
#define I_DIM 256
#define M_DIM (B_DIM * S_DIM)   // 32768 rows
#define N_DIM 1536              // 6*OUT gate columns
#define K_DIM 512               // WINDOW*I

// GEMM tiling: 256x256 tile, BK=64, 8 waves (2M x 4N), quadrant-scoped phases
#define BM 256
#define BN 256
#define EP_STRIDE 264           // fp16 m-stride of epilogue transpose chunk (256+8)

#define NX4 ((M_DIM * I_DIM) / 4)
#define NW4 ((N_DIM * K_DIM) / 4)

typedef __attribute__((ext_vector_type(8))) short bf16x8;
typedef __attribute__((ext_vector_type(4))) float f32x4;
typedef _Float16 h2 __attribute__((ext_vector_type(2)));
typedef _Float16 h4 __attribute__((ext_vector_type(4)));
typedef _Float16 h8 __attribute__((ext_vector_type(8)));

typedef const void __attribute__((address_space(1)))* gas_ptr;
typedef void __attribute__((address_space(3)))* las_ptr;

__device__ __forceinline__ void gload_lds16(const void* g, void* l) {
    __builtin_amdgcn_global_load_lds((gas_ptr)(uintptr_t)g, (las_ptr)(uintptr_t)l, 16, 0, 0);
}

// v_rcp_f32-based activations (~1 ulp; fp16 storage rounding dominates).
__device__ __forceinline__ float fast_rcp(float x) {
    return __builtin_amdgcn_rcpf(x);
}
__device__ __forceinline__ float fast_sigmoid(float x) {
    return fast_rcp(1.0f + __expf(-x));
}
__device__ __forceinline__ float fast_tanh(float x) {
    float ax = fabsf(x);
    float e = __expf(-2.0f * ax);
    float t = (1.0f - e) * fast_rcp(1.0f + e);
    return copysignf(t, x);
}

__device__ __forceinline__ unsigned short f2bf(float f) {
    uint32_t u = __float_as_uint(f);
    uint32_t r = (u + 0x7FFFu + ((u >> 16) & 1u)) >> 16;
    return (unsigned short)r;
}

// ---------------------------------------------------------------------------
// Single conversion kernel: x -> bf16, W -> bf16, zero page.
// ---------------------------------------------------------------------------
__global__ __launch_bounds__(256)
void cvt_all(const float* __restrict__ x, const float* __restrict__ W,
             unsigned short* __restrict__ xb, unsigned short* __restrict__ Wb,
             unsigned short* __restrict__ zp)
{
    int i = blockIdx.x * 256 + threadIdx.x;
    if (blockIdx.x == 0 && threadIdx.x < 64) zp[threadIdx.x] = 0;
    if (i < NX4) {
        float4 v = ((const float4*)x)[i];
        ushort4 o;
        o.x = f2bf(v.x); o.y = f2bf(v.y); o.z = f2bf(v.z); o.w = f2bf(v.w);
        ((ushort4*)xb)[i] = o;
    } else if (i < NX4 + NW4) {
        int j = i - NX4;
        float4 v = ((const float4*)W)[j];
        ushort4 o;
        o.x = f2bf(v.x); o.y = f2bf(v.y); o.z = f2bf(v.z); o.w = f2bf(v.w);
        ((ushort4*)Wb)[j] = o;
    }
}

// ---------------------------------------------------------------------------
// Windowed GEMM + bias -> PRE-ACTIVATION fp16, TRANSPOSED gT[col][m].
//
// 256x256 tile, BK=64, 8 waves, 2x64KB LDS double-buffer.
// QUADRANT-SCOPED 4-phase schedule (round-1 retry; fix = fragment liveness):
// phase (kk,mh): ds_read 4 A-frags (m-half mh) + 4 B-frags (re-read per phase,
// zero cross-phase liveness -> peak regs = acc 128 + frags 32) ; 16 MFMA.
// Staging of tile kt+1 -> buf^1, 2 gloads/phase:
//   ph0: B-q0,B-q1   ph1: B-q2,B-q3   ph2: A-q0,A-q2   ph3: A-q1,A-q3
// (B earliest: every phase reads all B rows; A-q0/q2 are the rows phase-0
//  reads (wm=0:0-63, wm=1:128-191), A-q1/q3 phase-1's.)
// Counted waits, never a mid-loop drain: vmcnt(2) at end of ph0 and ph3 only
// (completes the 6 oldest = exactly what the next phase reads; leaves 2 in
// flight). Reads and stages always target opposite buffers within a tile;
// cross-tile overwrite separated by >=3 barrier pairs. Staging/swizzle/
// epilogue machinery identical to round-1 (correctness-verified).
// A[m][k] = (k<256) ? x[b, s-1, k] (0 if s==0) : x[b, s, k-256]
// ---------------------------------------------------------------------------

#define SBAR __builtin_amdgcn_s_barrier()
#define LGK0 asm volatile("s_waitcnt lgkmcnt(0)" ::: "memory")
#define FENCE asm volatile("" ::: "memory")
#define VMW2 asm volatile("s_waitcnt vmcnt(2)" ::: "memory")
#define VMW0 asm volatile("s_waitcnt vmcnt(0)" ::: "memory")

#define STAGE_Bq(bufc, kt, q)                                                 \
    gload_lds16(W + (size_t)(n0 + (q) * 64 + w8 + l3) * 512 + (kt) * 64 + csx,\
                &smem[(bufc) * 32768 + 16384 + ((q) * 64 + w8) * 64]);

#define STAGE_Aq(bufc, kt, q)                                                 \
    { const int r_ = (q) * 64 + w8 + l3;                                      \
      const int srow_ = sBase + r_;                                           \
      const __hip_bfloat16* src_;                                             \
      if ((kt) < 4) {                                                         \
          src_ = (srow_ == 0) ? zeroPage                                      \
               : x + ((size_t)((bIdx << 12) + srow_ - 1) * 256 + (kt) * 64 + csx); \
      } else {                                                                \
          src_ = x + ((size_t)((bIdx << 12) + srow_) * 256 + ((kt) - 4) * 64 + csx); \
      }                                                                       \
      gload_lds16(src_, &smem[(bufc) * 32768 + ((q) * 64 + w8) * 64]); }

// VMW: 2 -> vmcnt(2), 0 -> vmcnt(0), -1 -> none
#define PHASE(bufc, kk, mh, STAGES, VMW)                                      \
    { bf16x8 af[4], bq[4];                                                    \
      const int ch8_ = (((kk) * 4 + lq) ^ (la & 7)) * 8;                      \
      _Pragma("unroll")                                                       \
      for (int i = 0; i < 4; ++i)                                             \
          af[i] = *(const bf16x8*)&smem[(bufc) * 32768                        \
                      + (wm * 128 + (mh) * 64 + i * 16 + la) * 64 + ch8_];    \
      _Pragma("unroll")                                                       \
      for (int j = 0; j < 4; ++j)                                             \
          bq[j] = *(const bf16x8*)&smem[(bufc) * 32768 + 16384                \
                      + (wn * 64 + j * 16 + la) * 64 + ch8_];                 \
      STAGES;                                                                 \
      FENCE; SBAR; LGK0;                                                      \
      __builtin_amdgcn_s_setprio(1);                                          \
      _Pragma("unroll")                                                       \
      for (int i = 0; i < 4; ++i)                                             \
          _Pragma("unroll")                                                   \
          for (int j = 0; j < 4; ++j)                                         \
              acc[(mh) * 4 + i][j] = __builtin_amdgcn_mfma_f32_16x16x32_bf16( \
                  af[i], bq[j], acc[(mh) * 4 + i][j], 0, 0, 0);               \
      __builtin_amdgcn_s_setprio(0);                                          \
      if ((VMW) == 2) { VMW2; } else if ((VMW) == 0) { VMW0; }                \
      FENCE; SBAR; }

__global__ __launch_bounds__(512, 2)
void qrnn_gemm(const __hip_bfloat16* __restrict__ x,
               const __hip_bfloat16* __restrict__ W,
               const float* __restrict__ bias,
               _Float16* __restrict__ gT,
               const __hip_bfloat16* __restrict__ zeroPage)
{
    __shared__ __hip_bfloat16 smem[65536];   // 128 KiB: [A0|B0|A1|B1]

    const int tid = threadIdx.x;
    const int wid = tid >> 6;
    const int l   = tid & 63;
    const int la = l & 15, lq = l >> 4;
    const int wm = wid >> 2, wn = wid & 3;
    const int w8 = wid * 8, l3 = l >> 3;
    const int csx = ((l & 7) ^ l3) * 8;      // pre-swizzled source chunk offset

    // XCD-bijective mapping: 768 blocks = 8 XCD x 96; tileN fast within band
    const int xcd  = blockIdx.x & 7;
    const int slot = blockIdx.x >> 3;        // 0..95
    const int tileN = slot % 6;
    const int tileM = xcd * 16 + slot / 6;   // 0..127
    const int m0 = tileM * BM;
    const int n0 = tileN * BN;
    const int bIdx  = m0 >> 12;
    const int sBase = m0 & 4095;

    f32x4 acc[8][4] = {};

    // ---- prologue: stage tile 0 into buf0 (phase staging order) ----
    STAGE_Bq(0, 0, 0); STAGE_Bq(0, 0, 1); STAGE_Bq(0, 0, 2); STAGE_Bq(0, 0, 3);
    STAGE_Aq(0, 0, 0); STAGE_Aq(0, 0, 2); STAGE_Aq(0, 0, 1); STAGE_Aq(0, 0, 3);
    VMW2;          // B all + A-q0,q2 landed; A-q1,q3 still in flight
    FENCE; SBAR;

    // ---- main loop: tiles 0..6 stage tile kt+1; tile 7 peeled ----
    for (int kt = 0; kt < 7; ++kt) {
        const int buf = kt & 1;
        const int kn  = kt + 1;
        PHASE(buf, 0, 0, { STAGE_Bq(buf ^ 1, kn, 0); STAGE_Bq(buf ^ 1, kn, 1); },  2);
        PHASE(buf, 0, 1, { STAGE_Bq(buf ^ 1, kn, 2); STAGE_Bq(buf ^ 1, kn, 3); }, -1);
        PHASE(buf, 1, 0, { STAGE_Aq(buf ^ 1, kn, 0); STAGE_Aq(buf ^ 1, kn, 2); }, -1);
        PHASE(buf, 1, 1, { STAGE_Aq(buf ^ 1, kn, 1); STAGE_Aq(buf ^ 1, kn, 3); },  2);
    }
    PHASE(1, 0, 0, {},  0);   // drain last 2 A-loads before ph1 reads them
    PHASE(1, 0, 1, {}, -1);
    PHASE(1, 1, 0, {}, -1);
    PHASE(1, 1, 1, {}, -1);

    // ---- epilogue: two 128-col halves through LDS transpose chunk ----
    _Float16* tsp = (_Float16*)smem;
#pragma unroll
    for (int h = 0; h < 2; ++h) {
        if (h) __syncthreads();
        if ((wn >> 1) == h) {
#pragma unroll
            for (int j = 0; j < 4; ++j) {
                const int colL = (wn & 1) * 64 + j * 16 + la;   // 0..127
                const float bv = bias[n0 + h * 128 + colL];
                _Float16* base = tsp + colL * EP_STRIDE + wm * 128 + lq * 4;
#pragma unroll
                for (int i = 0; i < 8; ++i) {
                    h4 hv;
#pragma unroll
                    for (int rr = 0; rr < 4; ++rr)
                        hv[rr] = (_Float16)(acc[i][j][rr] + bv);
                    *(h4*)(base + i * 16) = hv;
                }
            }
        }
        __syncthreads();
        // stream: 8 consecutive lanes = one column's 128B run
#pragma unroll
        for (int it = 0; it < 8; ++it) {
            const int col = (tid >> 3) + 64 * (it & 1);         // 0..127
            const int mch = (tid & 7) + 8 * (it >> 1);          // 0..31
            h8 v = *(const h8*)(tsp + col * EP_STRIDE + mch * 8);
            *(h8*)(gT + (size_t)(n0 + h * 128 + col) * 32768 + m0 + mch * 8) = v;
        }
    }
}

// ---------------------------------------------------------------------------
// Single scan kernel, carry-free (warm-up compose: prod f over 128 t < e^-20).
// Round-0 geometry, rcp-based activations (round-5 verified, current best).
// ---------------------------------------------------------------------------
__global__ __launch_bounds__(256)
void qrnn_scan(const _Float16* __restrict__ gT, float* __restrict__ out)
{
    __shared__ _Float16 oc[16 * 512];   // 16 KB: [channel][t]

    const int wv = threadIdx.x >> 6;
    const int l  = threadIdx.x & 63;
    const int tc  = blockIdx.x & 7;           // time chunk 0..7
    const int cg  = (blockIdx.x >> 3) & 15;   // channel group 0..15
    const int dir = (blockIdx.x >> 7) & 1;
    const int b   = blockIdx.x >> 8;
    const int t0  = tc * 512;

    const bool haveWarm = (dir == 0) ? (tc > 0) : (tc < 7);
    const int tw0 = (dir == 0) ? (t0 - 128) : (t0 + 512);

    // ---- upfront loads: 4 channels x {z,f,o} h8 + warm-up h2 ----
    h8 z8[4], f8[4], o8[4];
    h2 zw[4], fw[4];
#pragma unroll
    for (int cc = 0; cc < 4; ++cc) {
        const int oo = cg * 16 + wv * 4 + cc;
        const size_t colz = (size_t)(dir * 256 + oo) * 32768 + (b << 12);
        z8[cc] = *(const h8*)(gT + colz + t0 + l * 8);
        f8[cc] = *(const h8*)(gT + (size_t)512 * 32768 + colz + t0 + l * 8);
        o8[cc] = *(const h8*)(gT + (size_t)1024 * 32768 + colz + t0 + l * 8);
        if (haveWarm) {
            zw[cc] = *(const h2*)(gT + colz + tw0 + l * 2);
            fw[cc] = *(const h2*)(gT + (size_t)512 * 32768 + colz + tw0 + l * 2);
        }
    }

#pragma unroll
    for (int cc = 0; cc < 4; ++cc) {
        const int chl = wv * 4 + cc;

        // ---- warm-up: compose 128 preceding t (scan order) -> cinit ----
        float cinit = 0.0f;
        if (haveWarm) {
            float A = 1.0f, Bv = 0.0f;
            if (dir == 0) {
#pragma unroll
                for (int k = 0; k < 2; ++k) {
                    float f = fast_sigmoid((float)fw[cc][k]);
                    float g = (1.0f - f) * fast_tanh((float)zw[cc][k]);
                    Bv = f * Bv + g; A *= f;
                }
            } else {
#pragma unroll
                for (int k = 1; k >= 0; --k) {
                    float f = fast_sigmoid((float)fw[cc][k]);
                    float g = (1.0f - f) * fast_tanh((float)zw[cc][k]);
                    Bv = f * Bv + g; A *= f;
                }
            }
#pragma unroll
            for (int d = 1; d < 64; d <<= 1) {
                float Ao = __shfl_xor(A, d);
                float Bo = __shfl_xor(Bv, d);
                bool selfFirst = ((l & d) == 0);
                if (dir == 1) selfFirst = !selfFirst;
                if (selfFirst) { Bv = Ao * Bv + Bo; A = A * Ao; }
                else           { Bv = A * Bo + Bv; A = A * Ao; }
            }
            cinit = Bv;
        }

        // ---- local 8-step compose ----
        float fa[8], ga[8];
        float A = 1.0f, Bv = 0.0f;
        if (dir == 0) {
#pragma unroll
            for (int k = 0; k < 8; ++k) {
                fa[k] = fast_sigmoid((float)f8[cc][k]);
                ga[k] = (1.0f - fa[k]) * fast_tanh((float)z8[cc][k]);
                Bv = fa[k] * Bv + ga[k]; A *= fa[k];
            }
        } else {
#pragma unroll
            for (int k = 7; k >= 0; --k) {
                fa[k] = fast_sigmoid((float)f8[cc][k]);
                ga[k] = (1.0f - fa[k]) * fast_tanh((float)z8[cc][k]);
                Bv = fa[k] * Bv + ga[k]; A *= fa[k];
            }
        }

        // ---- wave-level exclusive scan ----
        float Ae, Be;
        if (dir == 0) {
#pragma unroll
            for (int d = 1; d < 64; d <<= 1) {
                float Ao = __shfl_up(A, d);
                float Bo = __shfl_up(Bv, d);
                if (l >= d) { Bv = A * Bo + Bv; A = A * Ao; }
            }
            Ae = __shfl_up(A, 1); Be = __shfl_up(Bv, 1);
            if (l == 0) { Ae = 1.0f; Be = 0.0f; }
        } else {
#pragma unroll
            for (int d = 1; d < 64; d <<= 1) {
                float Ao = __shfl_down(A, d);
                float Bo = __shfl_down(Bv, d);
                if (l + d < 64) { Bv = A * Bo + Bv; A = A * Ao; }
            }
            Ae = __shfl_down(A, 1); Be = __shfl_down(Bv, 1);
            if (l == 63) { Ae = 1.0f; Be = 0.0f; }
        }

        // ---- replay + output gate -> one h8 LDS write ----
        float s = Ae * cinit + Be;
        h8 res;
        if (dir == 0) {
#pragma unroll
            for (int k = 0; k < 8; ++k) {
                s = fa[k] * s + ga[k];
                res[k] = (_Float16)(fast_sigmoid((float)o8[cc][k]) * s);
            }
        } else {
#pragma unroll
            for (int k = 7; k >= 0; --k) {
                s = fa[k] * s + ga[k];
                res[k] = (_Float16)(fast_sigmoid((float)o8[cc][k]) * s);
            }
        }
        *(h8*)&oc[chl * 512 + l * 8] = res;
    }
    __syncthreads();

    // ---- readout: thread = 2 consecutive t rows, 64B per row ----
    const int t2 = threadIdx.x * 2;
    float r0[16], r1[16];
#pragma unroll
    for (int ch = 0; ch < 16; ++ch) {
        h2 v = *(const h2*)&oc[ch * 512 + t2];
        r0[ch] = (float)v[0];
        r1[ch] = (float)v[1];
    }
    const size_t row0 = (size_t)((b << 12) + t0 + t2);
    float* po0 = out + row0 * 512 + dir * 256 + cg * 16;
    float* po1 = po0 + 512;
    *(float4*)(po0)      = make_float4(r0[0], r0[1], r0[2], r0[3]);
    *(float4*)(po0 + 4)  = make_float4(r0[4], r0[5], r0[6], r0[7]);
    *(float4*)(po0 + 8)  = make_float4(r0[8], r0[9], r0[10], r0[11]);
    *(float4*)(po0 + 12) = make_float4(r0[12], r0[13], r0[14], r0[15]);
    *(float4*)(po1)      = make_float4(r1[0], r1[1], r1[2], r1[3]);
    *(float4*)(po1 + 4)  = make_float4(r1[4], r1[5], r1[6], r1[7]);
    *(float4*)(po1 + 8)  = make_float4(r1[8], r1[9], r1[10], r1[11]);
    *(float4*)(po1 + 12) = make_float4(r1[12], r1[13], r1[14], r1[15]);
}

// ---------------------------------------------------------------------------
extern "C" void kernel_launch(void* const* d_in, const int* in_sizes, int n_in,
                              void* d_out, int out_size, void* d_ws, size_t ws_size,
                              hipStream_t stream)
{
    const float* x    = (const float*)d_in[0];   // (8,4096,256) fp32
    const float* W    = (const float*)d_in[1];   // (1536,512)  fp32
    const float* bias = (const float*)d_in[2];   // (1536,)     fp32
    float* out = (float*)d_out;                  // (8,4096,512) fp32

    char* ws = (char*)d_ws;
    size_t off = 0;
    __hip_bfloat16* xb = (__hip_bfloat16*)(ws + off); off += (size_t)M_DIM * I_DIM * 2;
    __hip_bfloat16* Wb = (__hip_bfloat16*)(ws + off); off += (size_t)N_DIM * K_DIM * 2;
    _Float16* gT = (_Float16*)(ws + off); off += (size_t)N_DIM * M_DIM * 2;   // 100.7 MB
    unsigned short* zeroPage = (unsigned short*)(ws + off); off += 128;

    const int ncvt = NX4 + NW4;
    cvt_all<<<dim3((ncvt + 255) / 256), dim3(256), 0, stream>>>(
        x, W, (unsigned short*)xb, (unsigned short*)Wb, zeroPage);

    qrnn_gemm<<<dim3(768), dim3(512), 0, stream>>>(xb, Wb, bias, gT,
                                                   (const __hip_bfloat16*)zeroPage);

    qrnn_scan<<<dim3(B_DIM * 2 * 16 * 8), dim3(256), 0, stream>>>(gT, out);
}

// Round 7
// 178.304 us; speedup vs baseline: 1.0867x; 1.0867x over previous
//
#include <hip/hip_runtime.h>
#include <hip/hip_bf16.h>
#include <stdint.h>

// Problem constants
#define B_DIM 8
#define S_DIM 4096
#define I_DIM 256
#define M_DIM (B_DIM * S_DIM)   // 32768 rows
#define N_DIM 1536              // 6*OUT gate columns
#define K_DIM 512               // WINDOW*I

// GEMM tiling
#define TM 128
#define TN 128
#define BK 64
#define LT_STRIDE 136           // fp16 m-stride of epilogue transpose chunk (pad 8)

#define NX4 ((M_DIM * I_DIM) / 4)
#define NW4 ((N_DIM * K_DIM) / 4)

typedef __attribute__((ext_vector_type(8))) short bf16x8;
typedef __attribute__((ext_vector_type(4))) float f32x4;
typedef _Float16 h2 __attribute__((ext_vector_type(2)));
typedef _Float16 h4 __attribute__((ext_vector_type(4)));
typedef _Float16 h8 __attribute__((ext_vector_type(8)));

typedef const void __attribute__((address_space(1)))* gas_ptr;
typedef void __attribute__((address_space(3)))* las_ptr;

__device__ __forceinline__ void gload_lds16(const void* g, void* l) {
    __builtin_amdgcn_global_load_lds((gas_ptr)(uintptr_t)g, (las_ptr)(uintptr_t)l, 16, 0, 0);
}

// v_rcp_f32-based activations (~1 ulp; fp16 storage rounding dominates).
__device__ __forceinline__ float fast_rcp(float x) {
    return __builtin_amdgcn_rcpf(x);
}
__device__ __forceinline__ float fast_sigmoid(float x) {
    return fast_rcp(1.0f + __expf(-x));
}
// 5-op tanh: 2*sigmoid(2x)-1. Exact at 0; rcp(inf)=0 handles saturation.
__device__ __forceinline__ float fast_tanh(float x) {
    float e = __expf(-2.0f * x);
    return fmaf(2.0f, fast_rcp(1.0f + e), -1.0f);
}

__device__ __forceinline__ unsigned short f2bf(float f) {
    uint32_t u = __float_as_uint(f);
    uint32_t r = (u + 0x7FFFu + ((u >> 16) & 1u)) >> 16;
    return (unsigned short)r;
}

// ---------------------------------------------------------------------------
// Single conversion kernel: x -> bf16, W -> bf16, zero page.
// ---------------------------------------------------------------------------
__global__ __launch_bounds__(256)
void cvt_all(const float* __restrict__ x, const float* __restrict__ W,
             unsigned short* __restrict__ xb, unsigned short* __restrict__ Wb,
             unsigned short* __restrict__ zp)
{
    int i = blockIdx.x * 256 + threadIdx.x;
    if (blockIdx.x == 0 && threadIdx.x < 64) zp[threadIdx.x] = 0;
    if (i < NX4) {
        float4 v = ((const float4*)x)[i];
        ushort4 o;
        o.x = f2bf(v.x); o.y = f2bf(v.y); o.z = f2bf(v.z); o.w = f2bf(v.w);
        ((ushort4*)xb)[i] = o;
    } else if (i < NX4 + NW4) {
        int j = i - NX4;
        float4 v = ((const float4*)W)[j];
        ushort4 o;
        o.x = f2bf(v.x); o.y = f2bf(v.y); o.z = f2bf(v.z); o.w = f2bf(v.w);
        ((ushort4*)Wb)[j] = o;
    }
}

// ---------------------------------------------------------------------------
// Windowed GEMM + bias -> PRE-ACTIVATION fp16, TRANSPOSED gT[col][m].
// (EXACT round-5 kernel: 128x128 tile, m97-style K loop, XCD-aware remap,
//  two-half LDS-transpose epilogue. 62.5 us / 845 TF measured — the m97
//  structure ceiling. 8-phase ports failed twice at this shape: R1 spill,
//  R6 barrier overhead at K=512 with 1 block/CU. Closed.)
// A[m][k] = (k<256) ? x[b, s-1, k] (0 if s==0) : x[b, s, k-256]
// ---------------------------------------------------------------------------
__global__ __launch_bounds__(256, 2)
void qrnn_gemm(const __hip_bfloat16* __restrict__ x,
               const __hip_bfloat16* __restrict__ W,
               const float* __restrict__ bias,
               _Float16* __restrict__ gT,
               const __hip_bfloat16* __restrict__ zeroPage)
{
    __shared__ __hip_bfloat16 smem[TM * BK + TN * BK];   // 32 KB
    __hip_bfloat16* lA = smem;
    __hip_bfloat16* lB = smem + TM * BK;
    _Float16* tsp = (_Float16*)smem;                     // transpose chunk alias

    const int tid = threadIdx.x;
    const int w = tid >> 6;
    const int l = tid & 63;

    // XCD-aware tile mapping (perf heuristic only; any mapping is correct)
    const int xcd  = blockIdx.x & 7;
    const int slot = blockIdx.x >> 3;        // 0..383
    const int tileN = slot % 12;             // FAST within XCD band
    const int tileM = xcd * 32 + slot / 12;  // 0..255
    const int m0 = tileM * TM;
    const int n0 = tileN * TN;
    const int bIdx = m0 >> 12;
    const int sBase = m0 & 4095;

    const int c8 = (l & 7) ^ ((l >> 3) & 7);
    const int rowInP = w * 8 + (l >> 3);

    const int la = l & 15, lq = l >> 4;
    const int wm = w >> 1, wn = w & 1;

    f32x4 acc[4][4] = {};

    for (int kt = 0; kt < K_DIM / BK; ++kt) {
        __syncthreads();
        const int kcol = kt * 64 + c8 * 8;
#pragma unroll
        for (int p = 0; p < 4; ++p) {
            const int r = p * 32 + rowInP;
            const int srow = sBase + r;
            const __hip_bfloat16* srcA;
            if (kcol < 256) {
                srcA = (srow == 0) ? zeroPage
                     : x + ((size_t)((bIdx << 12) + srow - 1) * 256 + kcol);
            } else {
                srcA = x + ((size_t)((bIdx << 12) + srow) * 256 + (kcol - 256));
            }
            gload_lds16(srcA, &lA[p * 2048 + w * 512]);
            gload_lds16(W + ((size_t)(n0 + r) * 512 + kcol), &lB[p * 2048 + w * 512]);
        }
        __syncthreads();

#pragma unroll
        for (int kk = 0; kk < 2; ++kk) {
            bf16x8 af[4], bfr[4];
#pragma unroll
            for (int i = 0; i < 4; ++i) {
                const int ra = wm * 64 + i * 16 + la;
                const int ch = (kk * 4 + lq) ^ (ra & 7);
                af[i] = *(const bf16x8*)&lA[ra * 64 + ch * 8];
            }
#pragma unroll
            for (int j = 0; j < 4; ++j) {
                const int rb = wn * 64 + j * 16 + la;
                const int ch = (kk * 4 + lq) ^ (rb & 7);
                bfr[j] = *(const bf16x8*)&lB[rb * 64 + ch * 8];
            }
#pragma unroll
            for (int i = 0; i < 4; ++i)
#pragma unroll
                for (int j = 0; j < 4; ++j)
                    acc[i][j] = __builtin_amdgcn_mfma_f32_16x16x32_bf16(
                        af[i], bfr[j], acc[i][j], 0, 0, 0);
        }
    }

    // ---- epilogue: two 64-column halves through a 17.4 KB LDS chunk ----
    const int grp = tid >> 3;    // 0..31
    const int ln8 = tid & 7;
#pragma unroll
    for (int half = 0; half < 2; ++half) {
        __syncthreads();   // protect LDS (staging for half 0, prev chunk for half 1)
        if (wn == half) {
#pragma unroll
            for (int j = 0; j < 4; ++j) {
                const int colL = j * 16 + la;                // 0..63 in this half
                const float bv = bias[n0 + half * 64 + colL];
                _Float16* base = tsp + colL * LT_STRIDE + wm * 64 + lq * 4;
#pragma unroll
                for (int i = 0; i < 4; ++i) {
                    h4 hv;
#pragma unroll
                    for (int rr = 0; rr < 4; ++rr)
                        hv[rr] = (_Float16)(acc[i][j][rr] + bv);
                    *(h4*)(base + i * 16) = hv;
                }
            }
        }
        __syncthreads();
        // all 256 threads stream: 8 consecutive lanes = one column's 128B run
#pragma unroll
        for (int it = 0; it < 4; ++it) {
            const int colL = grp + 32 * (it & 1);            // 0..63
            const int mseg = ln8 + 8 * (it >> 1);            // 0..15
            h8 v = *(const h8*)(tsp + colL * LT_STRIDE + mseg * 8);
            *(h8*)(gT + (size_t)(n0 + half * 64 + colL) * 32768 + m0 + mseg * 8) = v;
        }
    }
}

// ---------------------------------------------------------------------------
// Single scan kernel, carry-free (warm-up compose: prod f over 128 t < e^-20).
// CHANGED (round 7): 512-thread blocks, 2 channels/thread (8 waves x 2 cc =
// same 16 ch/block, same 2048 blocks, same LDS/readout tiles). Halves each
// thread's serial chain (R3 counters: 21% occupancy, latency-bound with 4
// serial cc iterations), doubles wave parallelism, shrinks live registers.
// Math path identical to round-5 (rcp activations; tanh now the 5-op
// 2*sigmoid(2x)-1 form — exact at 0, saturates via rcp(inf)=0).
// ---------------------------------------------------------------------------
__global__ __launch_bounds__(512)
void qrnn_scan(const _Float16* __restrict__ gT, float* __restrict__ out)
{
    __shared__ _Float16 oc[16 * 512];   // 16 KB: [channel][t]

    const int wv = threadIdx.x >> 6;          // 0..7
    const int l  = threadIdx.x & 63;
    const int tc  = blockIdx.x & 7;           // time chunk 0..7
    const int cg  = (blockIdx.x >> 3) & 15;   // channel group 0..15
    const int dir = (blockIdx.x >> 7) & 1;
    const int b   = blockIdx.x >> 8;
    const int t0  = tc * 512;

    const bool haveWarm = (dir == 0) ? (tc > 0) : (tc < 7);
    const int tw0 = (dir == 0) ? (t0 - 128) : (t0 + 512);

    // ---- upfront loads: 2 channels x {z,f,o} h8 + warm-up h2 ----
    h8 z8[2], f8[2], o8[2];
    h2 zw[2], fw[2];
#pragma unroll
    for (int cc = 0; cc < 2; ++cc) {
        const int oo = cg * 16 + wv * 2 + cc;
        const size_t colz = (size_t)(dir * 256 + oo) * 32768 + (b << 12);
        z8[cc] = *(const h8*)(gT + colz + t0 + l * 8);
        f8[cc] = *(const h8*)(gT + (size_t)512 * 32768 + colz + t0 + l * 8);
        o8[cc] = *(const h8*)(gT + (size_t)1024 * 32768 + colz + t0 + l * 8);
        if (haveWarm) {
            zw[cc] = *(const h2*)(gT + colz + tw0 + l * 2);
            fw[cc] = *(const h2*)(gT + (size_t)512 * 32768 + colz + tw0 + l * 2);
        }
    }

#pragma unroll
    for (int cc = 0; cc < 2; ++cc) {
        const int chl = wv * 2 + cc;

        // ---- warm-up: compose 128 preceding t (scan order) -> cinit ----
        float cinit = 0.0f;
        if (haveWarm) {
            float A = 1.0f, Bv = 0.0f;
            if (dir == 0) {
#pragma unroll
                for (int k = 0; k < 2; ++k) {
                    float f = fast_sigmoid((float)fw[cc][k]);
                    float g = (1.0f - f) * fast_tanh((float)zw[cc][k]);
                    Bv = f * Bv + g; A *= f;
                }
            } else {
#pragma unroll
                for (int k = 1; k >= 0; --k) {
                    float f = fast_sigmoid((float)fw[cc][k]);
                    float g = (1.0f - f) * fast_tanh((float)zw[cc][k]);
                    Bv = f * Bv + g; A *= f;
                }
            }
#pragma unroll
            for (int d = 1; d < 64; d <<= 1) {
                float Ao = __shfl_xor(A, d);
                float Bo = __shfl_xor(Bv, d);
                bool selfFirst = ((l & d) == 0);
                if (dir == 1) selfFirst = !selfFirst;
                if (selfFirst) { Bv = Ao * Bv + Bo; A = A * Ao; }
                else           { Bv = A * Bo + Bv; A = A * Ao; }
            }
            cinit = Bv;
        }

        // ---- local 8-step compose ----
        float fa[8], ga[8];
        float A = 1.0f, Bv = 0.0f;
        if (dir == 0) {
#pragma unroll
            for (int k = 0; k < 8; ++k) {
                fa[k] = fast_sigmoid((float)f8[cc][k]);
                ga[k] = (1.0f - fa[k]) * fast_tanh((float)z8[cc][k]);
                Bv = fa[k] * Bv + ga[k]; A *= fa[k];
            }
        } else {
#pragma unroll
            for (int k = 7; k >= 0; --k) {
                fa[k] = fast_sigmoid((float)f8[cc][k]);
                ga[k] = (1.0f - fa[k]) * fast_tanh((float)z8[cc][k]);
                Bv = fa[k] * Bv + ga[k]; A *= fa[k];
            }
        }

        // ---- wave-level exclusive scan ----
        float Ae, Be;
        if (dir == 0) {
#pragma unroll
            for (int d = 1; d < 64; d <<= 1) {
                float Ao = __shfl_up(A, d);
                float Bo = __shfl_up(Bv, d);
                if (l >= d) { Bv = A * Bo + Bv; A = A * Ao; }
            }
            Ae = __shfl_up(A, 1); Be = __shfl_up(Bv, 1);
            if (l == 0) { Ae = 1.0f; Be = 0.0f; }
        } else {
#pragma unroll
            for (int d = 1; d < 64; d <<= 1) {
                float Ao = __shfl_down(A, d);
                float Bo = __shfl_down(Bv, d);
                if (l + d < 64) { Bv = A * Bo + Bv; A = A * Ao; }
            }
            Ae = __shfl_down(A, 1); Be = __shfl_down(Bv, 1);
            if (l == 63) { Ae = 1.0f; Be = 0.0f; }
        }

        // ---- replay + output gate -> one h8 LDS write ----
        float s = Ae * cinit + Be;
        h8 res;
        if (dir == 0) {
#pragma unroll
            for (int k = 0; k < 8; ++k) {
                s = fa[k] * s + ga[k];
                res[k] = (_Float16)(fast_sigmoid((float)o8[cc][k]) * s);
            }
        } else {
#pragma unroll
            for (int k = 7; k >= 0; --k) {
                s = fa[k] * s + ga[k];
                res[k] = (_Float16)(fast_sigmoid((float)o8[cc][k]) * s);
            }
        }
        *(h8*)&oc[chl * 512 + l * 8] = res;
    }
    __syncthreads();

    // ---- readout: thread = 1 t row, 64B per row (512 threads = 512 rows) ----
    const int t1 = threadIdx.x;
    float r0[16];
#pragma unroll
    for (int ch = 0; ch < 16; ++ch)
        r0[ch] = (float)oc[ch * 512 + t1];
    const size_t row0 = (size_t)((b << 12) + t0 + t1);
    float* po0 = out + row0 * 512 + dir * 256 + cg * 16;
    *(float4*)(po0)      = make_float4(r0[0], r0[1], r0[2], r0[3]);
    *(float4*)(po0 + 4)  = make_float4(r0[4], r0[5], r0[6], r0[7]);
    *(float4*)(po0 + 8)  = make_float4(r0[8], r0[9], r0[10], r0[11]);
    *(float4*)(po0 + 12) = make_float4(r0[12], r0[13], r0[14], r0[15]);
}

// ---------------------------------------------------------------------------
extern "C" void kernel_launch(void* const* d_in, const int* in_sizes, int n_in,
                              void* d_out, int out_size, void* d_ws, size_t ws_size,
                              hipStream_t stream)
{
    const float* x    = (const float*)d_in[0];   // (8,4096,256) fp32
    const float* W    = (const float*)d_in[1];   // (1536,512)  fp32
    const float* bias = (const float*)d_in[2];   // (1536,)     fp32
    float* out = (float*)d_out;                  // (8,4096,512) fp32

    char* ws = (char*)d_ws;
    size_t off = 0;
    __hip_bfloat16* xb = (__hip_bfloat16*)(ws + off); off += (size_t)M_DIM * I_DIM * 2;
    __hip_bfloat16* Wb = (__hip_bfloat16*)(ws + off); off += (size_t)N_DIM * K_DIM * 2;
    _Float16* gT = (_Float16*)(ws + off); off += (size_t)N_DIM * M_DIM * 2;   // 100.7 MB
    unsigned short* zeroPage = (unsigned short*)(ws + off); off += 128;

    const int ncvt = NX4 + NW4;
    cvt_all<<<dim3((ncvt + 255) / 256), dim3(256), 0, stream>>>(
        x, W, (unsigned short*)xb, (unsigned short*)Wb, zeroPage);

    qrnn_gemm<<<dim3(256 * 12), dim3(256), 0, stream>>>(xb, Wb, bias, gT,
                                                        (const __hip_bfloat16*)zeroPage);

    qrnn_scan<<<dim3(B_DIM * 2 * 16 * 8), dim3(512), 0, stream>>>(gT, out);
}